// Round 5
// baseline (890.388 us; speedup 1.0000x reference)
//
#include <hip/hip_runtime.h>
#include <hip/hip_bf16.h>
#include <cstdint>

#define NEG   (-1e30f)
#define VSZ   256      // vocab size (fixed for this problem)
#define TCAP  2048     // >= T = 2000
#define GLW   208      // gl row width (>= S+1, float4-aligned, < 256 to cut traffic)
#define SENTI 0x7fc00001  // qNaN payload sentinel for the ring (never produced by math)
#define LOG2E 1.4426950408889634f
#define LN2   0.6931471805599453f

__device__ __forceinline__ float fexp2(float x) { return __builtin_amdgcn_exp2f(x); }
__device__ __forceinline__ float flog2(float x) { return __builtin_amdgcn_logf(x); }

// one argument of the logsumexp is always the max -> its exp2 term is exactly 1
__device__ __forceinline__ float lae2b(float a, float b) {        // 1 exp + 1 log
    float mx = fmaxf(a, b), mn = fminf(a, b);
    return mx + flog2(1.0f + fexp2(mn - mx));
}
__device__ __forceinline__ float lae3b(float a, float b, float c) { // 2 exp + 1 log
    float mx = fmaxf(fmaxf(a, b), c);                 // v_max3
    float md = __builtin_amdgcn_fmed3f(a, b, c);      // v_med3
    float mn = fminf(fminf(a, b), c);                 // v_min3
    return mx + flog2(1.0f + fexp2(md - mx) + fexp2(mn - mx));
}

// ---------------------------------------------------------------------------
// Prep: per (b,t) row -> lse; gl[row][c] = (logit[lab[c]] - lse)*log2e for
// c in [0,GLW), bl[row] = (blank - lse)*log2e. 2 rows per wave (ILP on the
// shuffle-reduce chains), 8 rows per block, 2D grid (y = b) -> no int div.
// ---------------------------------------------------------------------------
__global__ __launch_bounds__(256) void prep_kernel(const float* __restrict__ logits,
                                                   const int* __restrict__ targets,
                                                   float* __restrict__ gl,
                                                   float* __restrict__ bl,
                                                   int T, int S) {
    const int b    = blockIdx.y;
    const int lane = threadIdx.x & 63;
    const int wv   = threadIdx.x >> 6;
    const int tr0  = blockIdx.x * 8 + wv * 2;      // first of 2 rows for this wave
    __shared__ float ldsrow[4][2][VSZ];

    const int* tg = targets + (size_t)b * S;

    #pragma unroll
    for (int rr = 0; rr < 2; ++rr) {
        int tr = tr0 + rr;
        if (tr >= T) break;
        size_t row = (size_t)b * T + tr;
        const float4* p = (const float4*)(logits + row * VSZ);
        float4 x = p[lane];
        ((float4*)&ldsrow[wv][rr][0])[lane] = x;

        float m = fmaxf(fmaxf(x.x, x.y), fmaxf(x.z, x.w));
        #pragma unroll
        for (int off = 32; off; off >>= 1) m = fmaxf(m, __shfl_xor(m, off, 64));
        float s = __expf(x.x - m) + __expf(x.y - m) + __expf(x.z - m) + __expf(x.w - m);
        #pragma unroll
        for (int off = 32; off; off >>= 1) s += __shfl_xor(s, off, 64);
        float lse = m + __logf(s);

        float* glr = gl + row * GLW;
        if (lane < GLW / 4) {
            int c0 = 4 * lane;
            int l0 = tg[min(c0,     S - 1)];
            int l1 = tg[min(c0 + 1, S - 1)];
            int l2 = tg[min(c0 + 2, S - 1)];
            int l3 = tg[min(c0 + 3, S - 1)];
            float4 o;
            o.x = (ldsrow[wv][rr][l0] - lse) * LOG2E;
            o.y = (ldsrow[wv][rr][l1] - lse) * LOG2E;
            o.z = (ldsrow[wv][rr][l2] - lse) * LOG2E;
            o.w = (ldsrow[wv][rr][l3] - lse) * LOG2E;
            *(float4*)&glr[c0] = o;
        }
        if (lane == 0) bl[row] = (x.x - lse) * LOG2E;
    }
}

// ---------------------------------------------------------------------------
// Scan v5: barrier-free wave pipeline. Thread i owns states 2i, 2i+1.
// Per step: neighbor odd state via __shfl_up inside a wave; across wave
// boundaries via a full-length LDS ring (no wrap, sentinel-tagged, volatile)
// with a one-step pre-read. Dependencies flow strictly downward in state, so
// producer waves never wait. Gather/blank values register-prefetched D=16.
// ---------------------------------------------------------------------------
__global__ __launch_bounds__(256, 1) void ctc_scan5(const float* __restrict__ gl,
                                                    const float* __restrict__ bl,
                                                    const int* __restrict__ targets,
                                                    const int* __restrict__ llen_p,
                                                    const int* __restrict__ tlen_p,
                                                    float* __restrict__ out,
                                                    int T, int S) {
    const int b    = blockIdx.x;
    const int i    = threadIdx.x;
    const int wave = i >> 6;
    const int lane = i & 63;
    const int len  = llen_p[b];

    __shared__ int   tgts[256];
    __shared__ float fin[512];
    __shared__ volatile int ring[3][TCAP];       // boundary w<->w+1 at ring[w]

    tgts[i] = targets[(size_t)b * S + min(i, S - 1)];
    for (int k = i; k < 3 * TCAP; k += 256) ((volatile int*)&ring[0][0])[k] = SENTI;
    __syncthreads();

    const bool skp = (i == 0) ? true : (tgts[i] != tgts[i - 1]);
    float W8 = (i == 0) ? 0.0f : NEG;            // state 2i
    float W9 = NEG;                              // state 2i+1

    const int ci = min(i, GLW - 1);
    const float* __restrict__ pg = gl + ((size_t)b * T) * GLW + ci;
    const float* __restrict__ pb = bl + (size_t)b * T;

    volatile int* ringIn  = (wave >= 1) ? &ring[wave - 1][0] : nullptr;
    volatile int* ringOut = (wave < 3)  ? &ring[wave][0]     : nullptr;

    // prefetch gather + blank, distance 16
    float G[16], BL[16];
    const int lm1 = len - 1;
    #pragma unroll
    for (int u = 0; u < 16; ++u) {
        int tt = min(u, lm1);
        G[u]  = pg[(size_t)tt * GLW];
        BL[u] = pb[tt];
    }

    int rv = SENTI;                               // pre-read slot for next step
    const int nch = (len + 15) >> 4;

    for (int c = 0; c < nch; ++c) {
        #pragma unroll
        for (int u = 0; u < 16; ++u) {
            const int t = (c << 4) + u;
            if (t < len) {                        // uniform branch
                float nb = __shfl_up(W9, 1, 64);  // old odd of thread i-1
                if (wave >= 1) {                  // uniform
                    if (t >= 1) {
                        while (__builtin_amdgcn_readfirstlane(rv) == SENTI)
                            rv = ringIn[t - 1];   // volatile re-read (rare)
                        if (lane == 0) nb = __int_as_float(rv);
                    } else if (lane == 0) nb = NEG;
                } else if (lane == 0) nb = NEG;

                float w9n = lae3b(W9, W8, skp ? nb : NEG) + G[u];  // state 2i+1
                float w8n = lae2b(W8, nb) + BL[u];                  // state 2i
                W8 = w8n; W9 = w9n;

                if (wave < 3 && lane == 63) ringOut[t] = __float_as_int(W9);
                if (wave >= 1) rv = ringIn[t];    // pre-read for step t+1

                int tt = min(t + 16, lm1);        // refill prefetch slot
                G[u]  = pg[(size_t)tt * GLW];
                BL[u] = pb[tt];
            }
        }
    }

    fin[2 * i]     = W8;
    fin[2 * i + 1] = W9;
    __syncthreads();
    if (i == 0) {
        int tl = tlen_p[b];
        out[b] = -lae2b(fin[2 * tl - 1], fin[2 * tl]) * LN2;
    }
}

// ---------------------------------------------------------------------------
// Fallback path (R2) if workspace is too small for the gather matrix.
// ---------------------------------------------------------------------------
__device__ __forceinline__ void barrier_lgkm() {
    __asm__ volatile("s_waitcnt lgkmcnt(0)\n\ts_barrier" ::: "memory");
}

__global__ __launch_bounds__(256) void lse_kernel(const float* __restrict__ logits,
                                                  float* __restrict__ lse,
                                                  int nrows) {
    int row = blockIdx.x * 4 + (threadIdx.x >> 6);
    if (row >= nrows) return;
    int lane = threadIdx.x & 63;
    const float4* p = (const float4*)(logits + (size_t)row * VSZ);
    float4 x = p[lane];
    float m = fmaxf(fmaxf(x.x, x.y), fmaxf(x.z, x.w));
    #pragma unroll
    for (int off = 32; off; off >>= 1) m = fmaxf(m, __shfl_xor(m, off, 64));
    float s = __expf(x.x - m) + __expf(x.y - m) + __expf(x.z - m) + __expf(x.w - m);
    #pragma unroll
    for (int off = 32; off; off >>= 1) s += __shfl_xor(s, off, 64);
    if (lane == 0) lse[row] = m + __logf(s);
}

__device__ __forceinline__ float lae(float a, float b) {
    float mx = fmaxf(a, b);
    float mn = fminf(a, b);
    return mx + __logf(1.0f + __expf(mn - mx));
}

__global__ __launch_bounds__(256, 1) void ctc_scan_fb(const float* __restrict__ logits,
                                                      const int* __restrict__ targets,
                                                      const int* __restrict__ llen_p,
                                                      const int* __restrict__ tlen_p,
                                                      const float* __restrict__ lse,
                                                      float* __restrict__ out,
                                                      int T, int S) {
    const int b = blockIdx.x;
    const int i = threadIdx.x;
    const int len = llen_p[b];

    __shared__ float blankv[TCAP];
    __shared__ float abuf[2][256 + 2];
    __shared__ float wsum[4];

    const float* __restrict__ lgb  = logits + (size_t)b * T * VSZ;
    const float* __restrict__ lseb = lse + (size_t)b * T;

    int  lab  = 0;
    bool skip = false;
    if (i < S) {
        lab = targets[b * S + i];
        int prev = (i >= 1) ? targets[b * S + i - 1] : -1;
        skip = (lab != prev);
    }
    for (int t = i; t < len; t += 256) blankv[t] = lgb[(size_t)t * VSZ];
    if (i < 2) abuf[i][0] = NEG;
    __syncthreads();

    float aEven = (i == 0) ? 0.0f : NEG;
    float aOdd  = NEG;
    const int lm1 = len - 1;
    float v0 = lgb[(size_t)lab];
    float v1 = lgb[(size_t)min(1, lm1) * VSZ + lab];
    float v2 = lgb[(size_t)min(2, lm1) * VSZ + lab];

    for (int t = 0; t < len; ++t) {
        float v3 = lgb[(size_t)min(t + 3, lm1) * VSZ + lab];
        float blv = blankv[t];
        abuf[t & 1][i + 1] = aOdd;
        barrier_lgkm();
        float nb = abuf[t & 1][i];
        float ne = lae(aEven, nb) + blv;
        float no = lae(lae(aOdd, aEven), skip ? nb : NEG) + v0;
        aEven = ne; aOdd = no;
        v0 = v1; v1 = v2; v2 = v3;
    }

    blankv[2 * i]     = aEven;
    blankv[2 * i + 1] = aOdd;
    float part = 0.f;
    for (int t = i; t < len; t += 256) part += lseb[t];
    #pragma unroll
    for (int off = 32; off; off >>= 1) part += __shfl_xor(part, off, 64);
    if ((i & 63) == 0) wsum[i >> 6] = part;
    __syncthreads();
    if (i == 0) {
        int tl = tlen_p[b];
        float s = wsum[0] + wsum[1] + wsum[2] + wsum[3];
        out[b] = s - lae(blankv[2 * tl - 1], blankv[2 * tl]);
    }
}

// ---------------------------------------------------------------------------
extern "C" void kernel_launch(void* const* d_in, const int* in_sizes, int n_in,
                              void* d_out, int out_size, void* d_ws, size_t ws_size,
                              hipStream_t stream) {
    const float* logits  = (const float*)d_in[0];
    const int*   targets = (const int*)d_in[1];
    const int*   llen    = (const int*)d_in[2];
    const int*   tlen    = (const int*)d_in[3];
    float*       out     = (float*)d_out;

    const int B = in_sizes[2];
    const int S = in_sizes[1] / B;
    const int T = in_sizes[0] / (B * VSZ);
    const int nrows = B * T;

    const size_t need = (size_t)nrows * GLW * sizeof(float) + (size_t)nrows * sizeof(float);
    if (ws_size >= need) {
        float* gl = (float*)d_ws;                       // nrows * GLW floats
        float* bl = (float*)d_ws + (size_t)nrows * GLW; // nrows floats
        dim3 grid((T + 7) / 8, B);
        prep_kernel<<<grid, 256, 0, stream>>>(logits, targets, gl, bl, T, S);
        ctc_scan5<<<B, 256, 0, stream>>>(gl, bl, targets, llen, tlen, out, T, S);
    } else {
        float* lse = (float*)d_ws;                      // nrows floats
        lse_kernel<<<(nrows + 3) / 4, 256, 0, stream>>>(logits, lse, nrows);
        ctc_scan_fb<<<B, 256, 0, stream>>>(logits, targets, llen, tlen, lse, out, T, S);
    }
}

// Round 6
// 697.747 us; speedup vs baseline: 1.2761x; 1.2761x over previous
//
#include <hip/hip_runtime.h>
#include <hip/hip_bf16.h>
#include <cstdint>

#define NEG  (-1e30f)
#define VSZ  256      // vocab size (fixed for this problem)
#define TCAP 2048     // >= T = 2000 (fallback path)
#define LN2F 0.6931471805599453f

static __device__ __forceinline__ float    uifu(unsigned u) { return __uint_as_float(u); }
static __device__ __forceinline__ unsigned f2bf(float f) {   // f >= 0, finite; RTE
    unsigned u = __float_as_uint(f);
    return (u + 0x7fffu + ((u >> 16) & 1u)) >> 16;
}

// ---------------------------------------------------------------------------
// Prep v6: one wave per (b,t) row. Computes lse, then writes
//   po[row][j]  = bf16( exp(logit[tg[j]] - lse) )   j in [0,256)  (odd states)
//   pbf[row]    = f32 ( exp(logit[0]     - lse) )                 (blank)
// ---------------------------------------------------------------------------
__global__ __launch_bounds__(256) void prep6(const float* __restrict__ logits,
                                             const int* __restrict__ targets,
                                             unsigned short* __restrict__ po,
                                             float* __restrict__ pbf,
                                             int T, int S) {
    const int b    = blockIdx.y;
    const int lane = threadIdx.x & 63;
    const int wv   = threadIdx.x >> 6;
    const int rt   = blockIdx.x * 4 + wv;
    if (rt >= T) return;
    const size_t row = (size_t)b * T + rt;
    __shared__ float ldsrow[4][VSZ];

    const float4* p = (const float4*)(logits + row * VSZ);
    float4 x = p[lane];
    ((float4*)&ldsrow[wv][0])[lane] = x;

    float m = fmaxf(fmaxf(x.x, x.y), fmaxf(x.z, x.w));
    #pragma unroll
    for (int off = 32; off; off >>= 1) m = fmaxf(m, __shfl_xor(m, off, 64));
    float s = __expf(x.x - m) + __expf(x.y - m) + __expf(x.z - m) + __expf(x.w - m);
    #pragma unroll
    for (int off = 32; off; off >>= 1) s += __shfl_xor(s, off, 64);
    float lse = m + __logf(s);

    const int* tg = targets + (size_t)b * S;
    const int c0 = 4 * lane;
    float pr0 = 0.f, pr1 = 0.f, pr2 = 0.f, pr3 = 0.f;
    if (c0     < S) pr0 = __expf(ldsrow[wv][tg[c0]]     - lse);
    if (c0 + 1 < S) pr1 = __expf(ldsrow[wv][tg[c0 + 1]] - lse);
    if (c0 + 2 < S) pr2 = __expf(ldsrow[wv][tg[c0 + 2]] - lse);
    if (c0 + 3 < S) pr3 = __expf(ldsrow[wv][tg[c0 + 3]] - lse);

    uint2 st;
    st.x = f2bf(pr0) | (f2bf(pr1) << 16);
    st.y = f2bf(pr2) | (f2bf(pr3) << 16);
    ((uint2*)(po + row * VSZ))[lane] = st;
    if (lane == 0) pbf[row] = __expf(x.x - lse);
}

// ---------------------------------------------------------------------------
// Scan v6: ONE WAVE per batch element; thread i owns extended states
// 8i..8i+7 (A0..A7) in linear-probability space with a per-thread integer
// exponent E (true alpha = A * 2^E). Per step: one __shfl_up for a[8i-1],
// 8 updates of (add,fma,mul), one uint2 bf16 load (prefetch depth 8), one
// wave-uniform blank prob. Renorm every 4 steps by the thread-local max's
// power of two (exact; invariant A*2^E preserved). Neighbor inflow scaled
// by 2^(E_{i-1}-E_i), clamped to +-126, recomputed once per window.
// No LDS, no barriers, no transcendentals in the loop.
// ---------------------------------------------------------------------------
__global__ __launch_bounds__(64, 1) void ctc_scan6(const unsigned short* __restrict__ po,
                                                   const float* __restrict__ pbf,
                                                   const int* __restrict__ targets,
                                                   const int* __restrict__ llen_p,
                                                   const int* __restrict__ tlen_p,
                                                   float* __restrict__ out,
                                                   int T, int S) {
    const int b = blockIdx.x;
    const int i = threadIdx.x;                 // 0..63
    const int len = llen_p[b];
    const int lm1 = len - 1;

    // skip masks for odd states 8i+1,+3,+5,+7  (j = 4i..4i+3)
    const int* tg  = targets + (size_t)b * S;
    const int Sm1  = S - 1;
    const int j0   = 4 * i;
    const int tm   = tg[max(min(j0 - 1, Sm1), 0)];
    const int t0   = tg[min(j0,     Sm1)];
    const int t1   = tg[min(j0 + 1, Sm1)];
    const int t2   = tg[min(j0 + 2, Sm1)];
    const int t3   = tg[min(j0 + 3, Sm1)];
    const float m1 = (j0 == 0 || t0 != tm) ? 1.f : 0.f;
    const float m3 = (t1 != t0) ? 1.f : 0.f;
    const float m5 = (t2 != t1) ? 1.f : 0.f;
    const float m7 = (t3 != t2) ? 1.f : 0.f;

    float A0 = (i == 0) ? 1.f : 0.f;
    float A1 = 0.f, A2 = 0.f, A3 = 0.f, A4 = 0.f, A5 = 0.f, A6 = 0.f, A7 = 0.f;
    int   E  = 0;
    float dscale = 1.f;                        // 2^(E_{i-1}-E_i) for this window

    const unsigned short* prow = po + ((size_t)b * T) * VSZ + 4 * i;
    const float*          pbr  = pbf + (size_t)b * T;

    uint2 R[8]; float PB[8];                   // prefetch ring, depth 8
    #pragma unroll
    for (int u = 0; u < 8; ++u) {
        int tt = min(u, lm1);
        R[u]  = *(const uint2*)(prow + (size_t)tt * VSZ);
        PB[u] = pbr[tt];
    }

    const int nch = (len + 7) >> 3;
    for (int c = 0; c < nch; ++c) {
        #pragma unroll
        for (int u = 0; u < 8; ++u) {
            const int t = 8 * c + u;
            if (t < len) {                     // wave-uniform branch
                float pA = uifu(R[u].x << 16);
                float pB = uifu(R[u].x & 0xffff0000u);
                float pC = uifu(R[u].y << 16);
                float pD = uifu(R[u].y & 0xffff0000u);
                float pb = PB[u];
                float hs = __shfl_up(A7, 1, 64) * dscale;   // old a[8i-1], rescaled
                if (i == 0) hs = 0.f;
                // descending slots: every read sees the OLD value
                float s7 = fmaf(m7, A5, A6) + A7;  A7 = s7 * pD;
                A6 = (A6 + A5) * pb;
                float s5 = fmaf(m5, A3, A4) + A5;  A5 = s5 * pC;
                A4 = (A4 + A3) * pb;
                float s3 = fmaf(m3, A1, A2) + A3;  A3 = s3 * pB;
                A2 = (A2 + A1) * pb;
                float s1 = fmaf(m1, hs, A0) + A1;  A1 = s1 * pA;
                A0 = (A0 + hs) * pb;
                // refill ring slot (consumed 8 steps from now)
                int tt = min(t + 8, lm1);
                R[u]  = *(const uint2*)(prow + (size_t)tt * VSZ);
                PB[u] = pbr[tt];
            }
            if (u == 3 || u == 7) {            // exact power-of-2 renorm
                float lm = fmaxf(fmaxf(fmaxf(A0, A1), fmaxf(A2, A3)),
                                 fmaxf(fmaxf(A4, A5), fmaxf(A6, A7)));
                unsigned mb = __float_as_uint(lm) >> 23;        // biased exponent
                float sc = uifu((254u - mb) << 23);             // 2^(127-mb)
                A0 *= sc; A1 *= sc; A2 *= sc; A3 *= sc;
                A4 *= sc; A5 *= sc; A6 *= sc; A7 *= sc;
                E += (int)mb - 127;
                int he = __shfl_up(E, 1, 64);
                int d  = min(max(he - E, -126), 126);
                dscale = uifu((unsigned)(d + 127) << 23);
            }
        }
    }

    __shared__ float fin[512];
    __shared__ int   fe[64];
    *(float4*)&fin[8 * i]     = make_float4(A0, A1, A2, A3);
    *(float4*)&fin[8 * i + 4] = make_float4(A4, A5, A6, A7);
    fe[i] = E;
    __syncthreads();
    if (i == 0) {
        int tl = tlen_p[b];
        int s1 = 2 * tl - 1, s2 = 2 * tl;
        float l1 = __logf(fin[s1]) + (float)fe[s1 >> 3] * LN2F;
        float l2 = __logf(fin[s2]) + (float)fe[s2 >> 3] * LN2F;
        float mx = fmaxf(l1, l2), mn = fminf(l1, l2);
        out[b] = -(mx + log1pf(__expf(mn - mx)));
    }
}

// ---------------------------------------------------------------------------
// Fallback (R2, known-good) if workspace is too small.
// ---------------------------------------------------------------------------
__device__ __forceinline__ void barrier_lgkm() {
    __asm__ volatile("s_waitcnt lgkmcnt(0)\n\ts_barrier" ::: "memory");
}

__global__ __launch_bounds__(256) void lse_kernel(const float* __restrict__ logits,
                                                  float* __restrict__ lse,
                                                  int nrows) {
    int row = blockIdx.x * 4 + (threadIdx.x >> 6);
    if (row >= nrows) return;
    int lane = threadIdx.x & 63;
    const float4* p = (const float4*)(logits + (size_t)row * VSZ);
    float4 x = p[lane];
    float m = fmaxf(fmaxf(x.x, x.y), fmaxf(x.z, x.w));
    #pragma unroll
    for (int off = 32; off; off >>= 1) m = fmaxf(m, __shfl_xor(m, off, 64));
    float s = __expf(x.x - m) + __expf(x.y - m) + __expf(x.z - m) + __expf(x.w - m);
    #pragma unroll
    for (int off = 32; off; off >>= 1) s += __shfl_xor(s, off, 64);
    if (lane == 0) lse[row] = m + __logf(s);
}

__device__ __forceinline__ float lae(float a, float b) {
    float mx = fmaxf(a, b);
    float mn = fminf(a, b);
    return mx + __logf(1.0f + __expf(mn - mx));
}

__global__ __launch_bounds__(256, 1) void ctc_scan_fb(const float* __restrict__ logits,
                                                      const int* __restrict__ targets,
                                                      const int* __restrict__ llen_p,
                                                      const int* __restrict__ tlen_p,
                                                      const float* __restrict__ lse,
                                                      float* __restrict__ out,
                                                      int T, int S) {
    const int b = blockIdx.x;
    const int i = threadIdx.x;
    const int len = llen_p[b];

    __shared__ float blankv[TCAP];
    __shared__ float abuf[2][256 + 2];
    __shared__ float wsum[4];

    const float* __restrict__ lgb  = logits + (size_t)b * T * VSZ;
    const float* __restrict__ lseb = lse + (size_t)b * T;

    int  lab  = 0;
    bool skip = false;
    if (i < S) {
        lab = targets[b * S + i];
        int prev = (i >= 1) ? targets[b * S + i - 1] : -1;
        skip = (lab != prev);
    }
    for (int t = i; t < len; t += 256) blankv[t] = lgb[(size_t)t * VSZ];
    if (i < 2) abuf[i][0] = NEG;
    __syncthreads();

    float aEven = (i == 0) ? 0.0f : NEG;
    float aOdd  = NEG;
    const int lm1 = len - 1;
    float v0 = lgb[(size_t)lab];
    float v1 = lgb[(size_t)min(1, lm1) * VSZ + lab];
    float v2 = lgb[(size_t)min(2, lm1) * VSZ + lab];

    for (int t = 0; t < len; ++t) {
        float v3 = lgb[(size_t)min(t + 3, lm1) * VSZ + lab];
        float blv = blankv[t];
        abuf[t & 1][i + 1] = aOdd;
        barrier_lgkm();
        float nb = abuf[t & 1][i];
        float ne = lae(aEven, nb) + blv;
        float no = lae(lae(aOdd, aEven), skip ? nb : NEG) + v0;
        aEven = ne; aOdd = no;
        v0 = v1; v1 = v2; v2 = v3;
    }

    blankv[2 * i]     = aEven;
    blankv[2 * i + 1] = aOdd;
    float part = 0.f;
    for (int t = i; t < len; t += 256) part += lseb[t];
    #pragma unroll
    for (int off = 32; off; off >>= 1) part += __shfl_xor(part, off, 64);
    if ((i & 63) == 0) wsum[i >> 6] = part;
    __syncthreads();
    if (i == 0) {
        int tl = tlen_p[b];
        float s = wsum[0] + wsum[1] + wsum[2] + wsum[3];
        out[b] = s - lae(blankv[2 * tl - 1], blankv[2 * tl]);
    }
}

// ---------------------------------------------------------------------------
extern "C" void kernel_launch(void* const* d_in, const int* in_sizes, int n_in,
                              void* d_out, int out_size, void* d_ws, size_t ws_size,
                              hipStream_t stream) {
    const float* logits  = (const float*)d_in[0];
    const int*   targets = (const int*)d_in[1];
    const int*   llen    = (const int*)d_in[2];
    const int*   tlen    = (const int*)d_in[3];
    float*       out     = (float*)d_out;

    const int B = in_sizes[2];
    const int S = in_sizes[1] / B;
    const int T = in_sizes[0] / (B * VSZ);
    const int nrows = B * T;

    const size_t need = (size_t)nrows * VSZ * sizeof(unsigned short)
                      + (size_t)nrows * sizeof(float);
    if (ws_size >= need) {
        unsigned short* po = (unsigned short*)d_ws;            // nrows*256 bf16
        float* pbf = (float*)(po + (size_t)nrows * VSZ);       // nrows f32
        dim3 grid((T + 3) / 4, B);
        prep6<<<grid, 256, 0, stream>>>(logits, targets, po, pbf, T, S);
        ctc_scan6<<<B, 64, 0, stream>>>(po, pbf, targets, llen, tlen, out, T, S);
    } else {
        float* lse = (float*)d_ws;                             // nrows f32
        lse_kernel<<<(nrows + 3) / 4, 256, 0, stream>>>(logits, lse, nrows);
        ctc_scan_fb<<<B, 256, 0, stream>>>(logits, targets, llen, tlen, lse, out, T, S);
    }
}

// Round 8
// 415.105 us; speedup vs baseline: 2.1450x; 1.6809x over previous
//
#include <hip/hip_runtime.h>
#include <hip/hip_bf16.h>
#include <cstdint>

#define NEG  (-1e30f)
#define VSZ  256      // vocab size (fixed for this problem)
#define TCAP 2048     // >= T = 2000 (fallback path)
#define LN2F 0.6931471805599453f

static __device__ __forceinline__ float    uifu(unsigned u) { return __uint_as_float(u); }
static __device__ __forceinline__ unsigned f2bf(float f) {   // f >= 0, finite; RTE
    unsigned u = __float_as_uint(f);
    return (u + 0x7fffu + ((u >> 16) & 1u)) >> 16;
}

// ---------------------------------------------------------------------------
// Prep: one wave per (b,t) row. Computes lse, then writes
//   po[row][j]  = bf16( exp(logit[tg[j]] - lse) )   j in [0,256)  (odd states)
//   pbf[row]    = f32 ( exp(logit[0]     - lse) )                 (blank)
// ---------------------------------------------------------------------------
__global__ __launch_bounds__(256) void prep6(const float* __restrict__ logits,
                                             const int* __restrict__ targets,
                                             unsigned short* __restrict__ po,
                                             float* __restrict__ pbf,
                                             int T, int S) {
    const int b    = blockIdx.y;
    const int lane = threadIdx.x & 63;
    const int wv   = threadIdx.x >> 6;
    const int rt   = blockIdx.x * 4 + wv;
    if (rt >= T) return;
    const size_t row = (size_t)b * T + rt;
    __shared__ float ldsrow[4][VSZ];

    const float4* p = (const float4*)(logits + row * VSZ);
    float4 x = p[lane];
    ((float4*)&ldsrow[wv][0])[lane] = x;

    float m = fmaxf(fmaxf(x.x, x.y), fmaxf(x.z, x.w));
    #pragma unroll
    for (int off = 32; off; off >>= 1) m = fmaxf(m, __shfl_xor(m, off, 64));
    float s = __expf(x.x - m) + __expf(x.y - m) + __expf(x.z - m) + __expf(x.w - m);
    #pragma unroll
    for (int off = 32; off; off >>= 1) s += __shfl_xor(s, off, 64);
    float lse = m + __logf(s);

    const int* tg = targets + (size_t)b * S;
    const int c0 = 4 * lane;
    float pr0 = 0.f, pr1 = 0.f, pr2 = 0.f, pr3 = 0.f;
    if (c0     < S) pr0 = __expf(ldsrow[wv][tg[c0]]     - lse);
    if (c0 + 1 < S) pr1 = __expf(ldsrow[wv][tg[c0 + 1]] - lse);
    if (c0 + 2 < S) pr2 = __expf(ldsrow[wv][tg[c0 + 2]] - lse);
    if (c0 + 3 < S) pr3 = __expf(ldsrow[wv][tg[c0 + 3]] - lse);

    uint2 st;
    st.x = f2bf(pr0) | (f2bf(pr1) << 16);
    st.y = f2bf(pr2) | (f2bf(pr3) << 16);
    ((uint2*)(po + row * VSZ))[lane] = st;
    if (lane == 0) pbf[row] = __expf(x.x - lse);
}

// ---------------------------------------------------------------------------
// Scan v8: one wave per batch element, linear-prob space with per-thread
// power-of-2 exponent. All prefetch state in NAMED registers (X-macros),
// refill distance 32, blank probs via readlane broadcast.
// Numeric safety vs v7 (which NaN'd): renorm every 4 steps, dscale clamp
// +-100 (peak thread value <= ~2^107, far from overflow), mb clamped <= 253
// so the renorm scale is always a normal positive float.
// ---------------------------------------------------------------------------
#define FOR16(M) M(0) M(1) M(2) M(3) M(4) M(5) M(6) M(7) \
                 M(8) M(9) M(10) M(11) M(12) M(13) M(14) M(15)

__global__ __launch_bounds__(64, 1) void ctc_scan8(const unsigned short* __restrict__ po,
                                                   const float* __restrict__ pbf,
                                                   const int* __restrict__ targets,
                                                   const int* __restrict__ llen_p,
                                                   const int* __restrict__ tlen_p,
                                                   float* __restrict__ out,
                                                   int T, int S) {
    const int b = blockIdx.x;
    const int i = threadIdx.x;                 // 0..63
    const int len = llen_p[b];
    const int lm1 = len - 1;

    // skip masks for odd states 8i+1,+3,+5,+7  (j = 4i..4i+3)
    const int* tg  = targets + (size_t)b * S;
    const int Sm1  = S - 1;
    const int j0   = 4 * i;
    const int tm   = tg[max(min(j0 - 1, Sm1), 0)];
    const int t0l  = tg[min(j0,     Sm1)];
    const int t1l  = tg[min(j0 + 1, Sm1)];
    const int t2l  = tg[min(j0 + 2, Sm1)];
    const int t3l  = tg[min(j0 + 3, Sm1)];
    const float m1 = (j0 == 0 || t0l != tm) ? 1.f : 0.f;
    const float m3 = (t1l != t0l) ? 1.f : 0.f;
    const float m5 = (t2l != t1l) ? 1.f : 0.f;
    const float m7 = (t3l != t2l) ? 1.f : 0.f;

    float A0 = (i == 0) ? 1.f : 0.f;
    float A1 = 0.f, A2 = 0.f, A3 = 0.f, A4 = 0.f, A5 = 0.f, A6 = 0.f, A7 = 0.f;
    int   E  = 0;
    float dscale = 1.f;                        // 2^(E_{i-1}-E_i) for this window

    const unsigned short* prow = po + ((size_t)b * T) * VSZ + 4 * i;
    const float*          pbr  = pbf + (size_t)b * T;
    const int q = i & 15;

    // named prefetch chunks
#define DCL(u) uint2 xa##u, xb##u;
    FOR16(DCL)
#undef DCL
#define LA(u) xa##u = *(const uint2*)(prow + (size_t)min(u, lm1) * VSZ);
    FOR16(LA)
#undef LA
#define LB(u) xb##u = *(const uint2*)(prow + (size_t)min(16 + u, lm1) * VSZ);
    FOR16(LB)
#undef LB
    float pbva = pbr[min(q, lm1)];
    float pbvb = pbr[min(16 + q, lm1)];

#define RENORM { \
    float lmx = fmaxf(fmaxf(fmaxf(A0, A1), fmaxf(A2, A3)), \
                      fmaxf(fmaxf(A4, A5), fmaxf(A6, A7))); \
    unsigned mb = __float_as_uint(lmx) >> 23; \
    mb = mb > 253u ? 253u : mb; \
    float sc_ = uifu((254u - mb) << 23); \
    A0 *= sc_; A1 *= sc_; A2 *= sc_; A3 *= sc_; \
    A4 *= sc_; A5 *= sc_; A6 *= sc_; A7 *= sc_; \
    E += (int)mb - 127; \
    int he = __shfl_up(E, 1, 64); \
    int d  = min(max(he - E, -100), 100); \
    dscale = uifu((unsigned)(d + 127) << 23); \
}

#define BODY(XREG, PBV) { \
    float pA = uifu(XREG.x << 16); \
    float pB = uifu(XREG.x & 0xffff0000u); \
    float pC = uifu(XREG.y << 16); \
    float pD = uifu(XREG.y & 0xffff0000u); \
    float hs = __shfl_up(A7, 1, 64) * dscale; \
    if (i == 0) hs = 0.f; \
    float s7 = fmaf(m7, A5, A6) + A7;  A7 = s7 * pD; \
    A6 = (A6 + A5) * (PBV); \
    float s5 = fmaf(m5, A3, A4) + A5;  A5 = s5 * pC; \
    A4 = (A4 + A3) * (PBV); \
    float s3 = fmaf(m3, A1, A2) + A3;  A3 = s3 * pB; \
    A2 = (A2 + A1) * (PBV); \
    float s1 = fmaf(m1, hs, A0) + A1;  A1 = s1 * pA; \
    A0 = (A0 + hs) * (PBV); \
}

#define STEPA(u) { \
    const int t = t0 + u; \
    if (t < len) { \
        float pb_ = __shfl(pbva, u, 64); \
        BODY(xa##u, pb_) \
    } \
    xa##u = *(const uint2*)(prow + (size_t)min(t0 + u + 32, lm1) * VSZ); \
    if (((u) & 3) == 3) RENORM \
}
#define STEPB(u) { \
    const int t = t0 + 16 + u; \
    if (t < len) { \
        float pb_ = __shfl(pbvb, u, 64); \
        BODY(xb##u, pb_) \
    } \
    xb##u = *(const uint2*)(prow + (size_t)min(t0 + u + 48, lm1) * VSZ); \
    if (((u) & 3) == 3) RENORM \
}

    int t0 = 0;
    const int nsup = (len + 31) >> 5;
    for (int sc2 = 0; sc2 < nsup; ++sc2) {
        float pna = pbr[min(t0 + 32 + q, lm1)];
        FOR16(STEPA)
        pbva = pna;
        float pnb = pbr[min(t0 + 48 + q, lm1)];
        FOR16(STEPB)
        pbvb = pnb;
        t0 += 32;
    }
#undef STEPA
#undef STEPB
#undef BODY
#undef RENORM

    __shared__ float fin[512];
    __shared__ int   fe[64];
    *(float4*)&fin[8 * i]     = make_float4(A0, A1, A2, A3);
    *(float4*)&fin[8 * i + 4] = make_float4(A4, A5, A6, A7);
    fe[i] = E;
    __syncthreads();
    if (i == 0) {
        int tl = tlen_p[b];
        int s1i = 2 * tl - 1, s2i = 2 * tl;
        float l1 = __logf(fin[s1i]) + (float)fe[s1i >> 3] * LN2F;
        float l2 = __logf(fin[s2i]) + (float)fe[s2i >> 3] * LN2F;
        float mx = fmaxf(l1, l2), mn = fminf(l1, l2);
        out[b] = -(mx + log1pf(__expf(mn - mx)));
    }
}

// ---------------------------------------------------------------------------
// Fallback (R2, known-good) if workspace is too small.
// ---------------------------------------------------------------------------
__device__ __forceinline__ void barrier_lgkm() {
    __asm__ volatile("s_waitcnt lgkmcnt(0)\n\ts_barrier" ::: "memory");
}

__global__ __launch_bounds__(256) void lse_kernel(const float* __restrict__ logits,
                                                  float* __restrict__ lse,
                                                  int nrows) {
    int row = blockIdx.x * 4 + (threadIdx.x >> 6);
    if (row >= nrows) return;
    int lane = threadIdx.x & 63;
    const float4* p = (const float4*)(logits + (size_t)row * VSZ);
    float4 x = p[lane];
    float m = fmaxf(fmaxf(x.x, x.y), fmaxf(x.z, x.w));
    #pragma unroll
    for (int off = 32; off; off >>= 1) m = fmaxf(m, __shfl_xor(m, off, 64));
    float s = __expf(x.x - m) + __expf(x.y - m) + __expf(x.z - m) + __expf(x.w - m);
    #pragma unroll
    for (int off = 32; off; off >>= 1) s += __shfl_xor(s, off, 64);
    if (lane == 0) lse[row] = m + __logf(s);
}

__device__ __forceinline__ float lae(float a, float b) {
    float mx = fmaxf(a, b);
    float mn = fminf(a, b);
    return mx + __logf(1.0f + __expf(mn - mx));
}

__global__ __launch_bounds__(256, 1) void ctc_scan_fb(const float* __restrict__ logits,
                                                      const int* __restrict__ targets,
                                                      const int* __restrict__ llen_p,
                                                      const int* __restrict__ tlen_p,
                                                      const float* __restrict__ lse,
                                                      float* __restrict__ out,
                                                      int T, int S) {
    const int b = blockIdx.x;
    const int i = threadIdx.x;
    const int len = llen_p[b];

    __shared__ float blankv[TCAP];
    __shared__ float abuf[2][256 + 2];
    __shared__ float wsum[4];

    const float* __restrict__ lgb  = logits + (size_t)b * T * VSZ;
    const float* __restrict__ lseb = lse + (size_t)b * T;

    int  lab  = 0;
    bool skip = false;
    if (i < S) {
        lab = targets[b * S + i];
        int prev = (i >= 1) ? targets[b * S + i - 1] : -1;
        skip = (lab != prev);
    }
    for (int t = i; t < len; t += 256) blankv[t] = lgb[(size_t)t * VSZ];
    if (i < 2) abuf[i][0] = NEG;
    __syncthreads();

    float aEven = (i == 0) ? 0.0f : NEG;
    float aOdd  = NEG;
    const int lm1 = len - 1;
    float v0 = lgb[(size_t)lab];
    float v1 = lgb[(size_t)min(1, lm1) * VSZ + lab];
    float v2 = lgb[(size_t)min(2, lm1) * VSZ + lab];

    for (int t = 0; t < len; ++t) {
        float v3 = lgb[(size_t)min(t + 3, lm1) * VSZ + lab];
        float blv = blankv[t];
        abuf[t & 1][i + 1] = aOdd;
        barrier_lgkm();
        float nb = abuf[t & 1][i];
        float ne = lae(aEven, nb) + blv;
        float no = lae(lae(aOdd, aEven), skip ? nb : NEG) + v0;
        aEven = ne; aOdd = no;
        v0 = v1; v1 = v2; v2 = v3;
    }

    blankv[2 * i]     = aEven;
    blankv[2 * i + 1] = aOdd;
    float part = 0.f;
    for (int t = i; t < len; t += 256) part += lseb[t];
    #pragma unroll
    for (int off = 32; off; off >>= 1) part += __shfl_xor(part, off, 64);
    if ((i & 63) == 0) wsum[i >> 6] = part;
    __syncthreads();
    if (i == 0) {
        int tl = tlen_p[b];
        float s = wsum[0] + wsum[1] + wsum[2] + wsum[3];
        out[b] = s - lae(blankv[2 * tl - 1], blankv[2 * tl]);
    }
}

// ---------------------------------------------------------------------------
extern "C" void kernel_launch(void* const* d_in, const int* in_sizes, int n_in,
                              void* d_out, int out_size, void* d_ws, size_t ws_size,
                              hipStream_t stream) {
    const float* logits  = (const float*)d_in[0];
    const int*   targets = (const int*)d_in[1];
    const int*   llen    = (const int*)d_in[2];
    const int*   tlen    = (const int*)d_in[3];
    float*       out     = (float*)d_out;

    const int B = in_sizes[2];
    const int S = in_sizes[1] / B;
    const int T = in_sizes[0] / (B * VSZ);
    const int nrows = B * T;

    const size_t need = (size_t)nrows * VSZ * sizeof(unsigned short)
                      + (size_t)nrows * sizeof(float);
    if (ws_size >= need) {
        unsigned short* po = (unsigned short*)d_ws;            // nrows*256 bf16
        float* pbf = (float*)(po + (size_t)nrows * VSZ);       // nrows f32
        dim3 grid((T + 3) / 4, B);
        prep6<<<grid, 256, 0, stream>>>(logits, targets, po, pbf, T, S);
        ctc_scan8<<<B, 64, 0, stream>>>(po, pbf, targets, llen, tlen, out, T, S);
    } else {
        float* lse = (float*)d_ws;                             // nrows f32
        lse_kernel<<<(nrows + 3) / 4, 256, 0, stream>>>(logits, lse, nrows);
        ctc_scan_fb<<<B, 256, 0, stream>>>(logits, targets, llen, tlen, lse, out, T, S);
    }
}